// Round 8
// baseline (25.699 us; speedup 1.0000x reference)
//
#include <hip/hip_runtime.h>
#include <cmath>

constexpr int B_ = 16, N_ = 10, H_ = 400, W_ = 400;
constexpr int HW = H_ * W_;              // 160000
constexpr int BN = B_ * N_;              // 160
constexpr int SPLITS = 8;                // 1280 blocks = exactly 5/CU, balanced
constexpr int CHUNK4 = HW / 4 / SPLITS;  // 5000 float4s per stripe
constexpr int NBLK = BN * SPLITS;        // 1280

// ws layout (distinct slot per block -> no zeroing, no atomics).
// Coalesced for finalize: slot = s*BN + bn (consecutive bn adjacent).
//   [0, NBLK)                overlap partials
//   [OFF_I, OFF_I+NBLK)      inter partials
//   [OFF_T, OFF_T+B_*SPLITS) tgt_area partials (n==0 blocks), slot = s*B_+b
constexpr int OFF_I = NBLK;
constexpr int OFF_T = 2 * NBLK;

__device__ __forceinline__ void body(const float4& o, const float4& t,
                                     int fi, int x1, int y1, int x2, int y2,
                                     float& accO, float& accT, float& accI) {
    accO += o.x * t.x + o.y * t.y + o.z * t.z + o.w * t.w;
    accT += t.x + t.y + t.z + t.w;
    int r = fi / W_;           // W_=400: a float4 never crosses a row
    int c = fi - r * W_;
    if (r >= y1 && r < y2) {
        float ix = (c     >= x1 && c     < x2) ? t.x : 0.0f;
        float iy = (c + 1 >= x1 && c + 1 < x2) ? t.y : 0.0f;
        float iz = (c + 2 >= x1 && c + 2 < x2) ? t.z : 0.0f;
        float iw = (c + 3 >= x1 && c + 3 < x2) ? t.w : 0.0f;
        accI += ix + iy + iz + iw;
    }
}

__global__ void __launch_bounds__(256)
fused_k(const float4* __restrict__ om, const float4* __restrict__ tm,
        const float* __restrict__ bboxes, float* __restrict__ ws) {
    __shared__ float smO[4], smI[4], smT[4];
    int bn = blockIdx.x / SPLITS;
    int s  = blockIdx.x % SPLITS;
    int b  = bn / N_;
    int n  = bn % N_;

    float4 bb = reinterpret_cast<const float4*>(bboxes)[bn];
    int x1 = (int)floorf(bb.x), y1 = (int)floorf(bb.y);
    int x2 = (int)floorf(bb.z), y2 = (int)floorf(bb.w);

    const float4* omp = om + (size_t)bn * (HW / 4) + (size_t)s * CHUNK4;
    const float4* tmp = tm + (size_t)b  * (HW / 4) + (size_t)s * CHUNK4;
    int fbase = s * CHUNK4 * 4;

    // 4 independent accumulator sets + 4-deep unroll: 4 om/tm float4 pairs
    // in flight per thread regardless of scheduling (anti-latency-collapse)
    float accO0 = 0.f, accT0 = 0.f, accI0 = 0.f;
    float accO1 = 0.f, accT1 = 0.f, accI1 = 0.f;
    float accO2 = 0.f, accT2 = 0.f, accI2 = 0.f;
    float accO3 = 0.f, accT3 = 0.f, accI3 = 0.f;
    for (int i = threadIdx.x; i < CHUNK4; i += 1024) {
        int i1 = i + 256, i2 = i + 512, i3 = i + 768;
        float4 o0 = omp[i];
        float4 t0 = tmp[i];
        float4 o1, t1, o2, t2, o3, t3;
        bool v1 = i1 < CHUNK4, v2 = i2 < CHUNK4, v3 = i3 < CHUNK4;
        if (v1) { o1 = omp[i1]; t1 = tmp[i1]; }
        if (v2) { o2 = omp[i2]; t2 = tmp[i2]; }
        if (v3) { o3 = omp[i3]; t3 = tmp[i3]; }
        body(o0, t0, fbase + i  * 4, x1, y1, x2, y2, accO0, accT0, accI0);
        if (v1) body(o1, t1, fbase + i1 * 4, x1, y1, x2, y2, accO1, accT1, accI1);
        if (v2) body(o2, t2, fbase + i2 * 4, x1, y1, x2, y2, accO2, accT2, accI2);
        if (v3) body(o3, t3, fbase + i3 * 4, x1, y1, x2, y2, accO3, accT3, accI3);
    }
    float accO = (accO0 + accO1) + (accO2 + accO3);
    float accT = (accT0 + accT1) + (accT2 + accT3);
    float accI = (accI0 + accI1) + (accI2 + accI3);

#pragma unroll
    for (int off = 32; off > 0; off >>= 1) {
        accO += __shfl_down(accO, off, 64);
        accI += __shfl_down(accI, off, 64);
        accT += __shfl_down(accT, off, 64);
    }
    int lane = threadIdx.x & 63, wid = threadIdx.x >> 6;
    if (lane == 0) { smO[wid] = accO; smI[wid] = accI; smT[wid] = accT; }
    __syncthreads();
    if (threadIdx.x == 0) {
        int slot = s * BN + bn;  // coalesced for finalize
        ws[slot]         = smO[0] + smO[1] + smO[2] + smO[3];
        ws[OFF_I + slot] = smI[0] + smI[1] + smI[2] + smI[3];
        if (n == 0)
            ws[OFF_T + s * B_ + b] = smT[0] + smT[1] + smT[2] + smT[3];
    }
}

__global__ void __launch_bounds__(256)
finalize_k(const float* __restrict__ bboxes, const float* __restrict__ ws,
           float* __restrict__ out) {
    int bn = threadIdx.x;
    if (bn >= BN) return;
    int b = bn / N_;
    float ov = 0.0f, inter = 0.0f, tgt = 0.0f;
#pragma unroll
    for (int s = 0; s < SPLITS; ++s) {
        ov    += ws[s * BN + bn];            // coalesced across threads
        inter += ws[OFF_I + s * BN + bn];
        tgt   += ws[OFF_T + s * B_ + b];
    }
    float4 bb = reinterpret_cast<const float4*>(bboxes)[bn];
    int x1 = (int)floorf(bb.x), y1 = (int)floorf(bb.y);
    int x2 = (int)floorf(bb.z), y2 = (int)floorf(bb.w);
    float cr = (float)max(0, min(y2, H_) - max(y1, 0));
    float cc = (float)max(0, min(x2, W_) - max(x1, 0));
    float box_area = cr * cc;
    float iou = inter / (box_area + tgt - inter + 1e-8f);
    out[bn * 2 + 0] = ov;
    out[bn * 2 + 1] = iou;
}

extern "C" void kernel_launch(void* const* d_in, const int* in_sizes, int n_in,
                              void* d_out, int out_size, void* d_ws, size_t ws_size,
                              hipStream_t stream) {
    const float*  bboxes = (const float*)d_in[0];
    const float4* om     = (const float4*)d_in[1];
    const float4* tm     = (const float4*)d_in[2];
    float* out = (float*)d_out;
    float* ws  = (float*)d_ws;

    fused_k<<<NBLK, 256, 0, stream>>>(om, tm, bboxes, ws);
    finalize_k<<<1, 256, 0, stream>>>(bboxes, ws, out);
}

// Round 9
// 24.842 us; speedup vs baseline: 1.0345x; 1.0345x over previous
//
#include <hip/hip_runtime.h>
#include <cmath>

constexpr int B_ = 16, N_ = 10, H_ = 400, W_ = 400;
constexpr int HW = H_ * W_;              // 160000
constexpr int BN = B_ * N_;              // 160
constexpr int SPLITS = 8;                // stripes per image; 1280 blocks co-resident
constexpr int CHUNK4 = HW / 4 / SPLITS;  // 5000 float4s per stripe
constexpr int NBLK = BN * SPLITS;        // 1280

// ws layout (distinct slot per block, every slot written every call -> no
// zeroing, no atomics):
//   [0, NBLK)               overlap partials, slot = blockIdx
//   [OFF_I, OFF_I+NBLK)     inter partials
//   [OFF_T, OFF_T+B_*SPLITS) tgt_area partials (n==0 blocks)
constexpr int OFF_I = NBLK;
constexpr int OFF_T = 2 * NBLK;

__device__ __forceinline__ void body(const float4& o, const float4& t,
                                     int fi, int x1, int y1, int x2, int y2,
                                     float& accO, float& accT, float& accI) {
    accO += o.x * t.x + o.y * t.y + o.z * t.z + o.w * t.w;
    accT += t.x + t.y + t.z + t.w;
    int r = fi / W_;           // W_=400: a float4 never crosses a row
    int c = fi - r * W_;
    if (r >= y1 && r < y2) {
        float ix = (c     >= x1 && c     < x2) ? t.x : 0.0f;
        float iy = (c + 1 >= x1 && c + 1 < x2) ? t.y : 0.0f;
        float iz = (c + 2 >= x1 && c + 2 < x2) ? t.z : 0.0f;
        float iw = (c + 3 >= x1 && c + 3 < x2) ? t.w : 0.0f;
        accI += ix + iy + iz + iw;
    }
}

__global__ void __launch_bounds__(256)
fused_k(const float4* __restrict__ om, const float4* __restrict__ tm,
        const float* __restrict__ bboxes, float* __restrict__ ws) {
    __shared__ float smO[4], smI[4], smT[4];
    int bn = blockIdx.x / SPLITS;
    int s  = blockIdx.x % SPLITS;
    int b  = bn / N_;
    int n  = bn % N_;

    float4 bb = reinterpret_cast<const float4*>(bboxes)[bn];
    int x1 = (int)floorf(bb.x), y1 = (int)floorf(bb.y);
    int x2 = (int)floorf(bb.z), y2 = (int)floorf(bb.w);

    const float4* omp = om + (size_t)bn * (HW / 4) + (size_t)s * CHUNK4;
    const float4* tmp = tm + (size_t)b  * (HW / 4) + (size_t)s * CHUNK4;
    int fbase = s * CHUNK4 * 4;

    // two independent accumulator sets + 2-deep unroll: >=2 float4 pairs in
    // flight regardless of register allocation (guards vs the R6 collapse)
    float accO0 = 0.f, accT0 = 0.f, accI0 = 0.f;
    float accO1 = 0.f, accT1 = 0.f, accI1 = 0.f;
    for (int i = threadIdx.x; i < CHUNK4; i += 512) {
        float4 o0 = omp[i];
        float4 t0 = tmp[i];
        int j = i + 256;
        if (j < CHUNK4) {
            float4 o1 = omp[j];
            float4 t1 = tmp[j];
            body(o1, t1, fbase + j * 4, x1, y1, x2, y2, accO1, accT1, accI1);
        }
        body(o0, t0, fbase + i * 4, x1, y1, x2, y2, accO0, accT0, accI0);
    }
    float accO = accO0 + accO1, accT = accT0 + accT1, accI = accI0 + accI1;

#pragma unroll
    for (int off = 32; off > 0; off >>= 1) {
        accO += __shfl_down(accO, off, 64);
        accI += __shfl_down(accI, off, 64);
        accT += __shfl_down(accT, off, 64);
    }
    int lane = threadIdx.x & 63, wid = threadIdx.x >> 6;
    if (lane == 0) { smO[wid] = accO; smI[wid] = accI; smT[wid] = accT; }
    __syncthreads();
    if (threadIdx.x == 0) {
        ws[blockIdx.x]         = smO[0] + smO[1] + smO[2] + smO[3];
        ws[OFF_I + blockIdx.x] = smI[0] + smI[1] + smI[2] + smI[3];
        if (n == 0)
            ws[OFF_T + b * SPLITS + s] = smT[0] + smT[1] + smT[2] + smT[3];
    }
}

__global__ void __launch_bounds__(256)
finalize_k(const float* __restrict__ bboxes, const float* __restrict__ ws,
           float* __restrict__ out) {
    int bn = threadIdx.x;
    if (bn >= BN) return;
    int b = bn / N_;
    float ov = 0.0f, inter = 0.0f, tgt = 0.0f;
#pragma unroll
    for (int s = 0; s < SPLITS; ++s) {
        ov    += ws[bn * SPLITS + s];
        inter += ws[OFF_I + bn * SPLITS + s];
        tgt   += ws[OFF_T + b * SPLITS + s];
    }
    float4 bb = reinterpret_cast<const float4*>(bboxes)[bn];
    int x1 = (int)floorf(bb.x), y1 = (int)floorf(bb.y);
    int x2 = (int)floorf(bb.z), y2 = (int)floorf(bb.w);
    float cr = (float)max(0, min(y2, H_) - max(y1, 0));
    float cc = (float)max(0, min(x2, W_) - max(x1, 0));
    float box_area = cr * cc;
    float iou = inter / (box_area + tgt - inter + 1e-8f);
    out[bn * 2 + 0] = ov;
    out[bn * 2 + 1] = iou;
}

extern "C" void kernel_launch(void* const* d_in, const int* in_sizes, int n_in,
                              void* d_out, int out_size, void* d_ws, size_t ws_size,
                              hipStream_t stream) {
    const float*  bboxes = (const float*)d_in[0];
    const float4* om     = (const float4*)d_in[1];
    const float4* tm     = (const float4*)d_in[2];
    float* out = (float*)d_out;
    float* ws  = (float*)d_ws;

    fused_k<<<NBLK, 256, 0, stream>>>(om, tm, bboxes, ws);
    finalize_k<<<1, 256, 0, stream>>>(bboxes, ws, out);
}